// Round 5
// baseline (193.746 us; speedup 1.0000x reference)
//
#include <hip/hip_runtime.h>
#include <math.h>

#define BATCH 32768
#define NE 9
#define RANK 50
#define DIM 450            // NE * RANK
#define REL_DIM 900        // 2 * DIM
#define N_REL 22
#define EPSV 2.2204460492503131e-16f
#define SPB 4              // samples per (single-wave) block in k_main

// Zero-instruction compiler fence: keeps LDS write->read program order across
// the cross-lane handoff points. No s_waitcnt is forced (unlike __syncthreads,
// which drains vmcnt(0) and would kill the cross-sample prefetch pipeline).
// HW ordering is free: single-wave blocks + per-wave in-order DS pipe.
#define LANE_FENCE() asm volatile("" ::: "memory")

__device__ __forceinline__ float softplusf(float x) {
    return (x > 20.f) ? x : log1pf(expf(x));
}
__device__ __forceinline__ float phif(float z) {
    return 0.5f * (1.f + erff(z * 0.70710678118654752f));
}

// Per-relation precompute: pure-rel conv outputs' dot contributions (o in [48,128)),
// Givens cos/sin table, softplus(c). 22 blocks.
__global__ __launch_bounds__(64) void k_pre(
    const float* __restrict__ rel, const float* __restrict__ rel_diag,
    const float* __restrict__ c_param,
    const float* __restrict__ cnn_w, const float* __restrict__ cnn_b,
    const float* __restrict__ cnnn_w, const float* __restrict__ cnnn_b,
    const float* __restrict__ h2e_w, const float* __restrict__ h2en_w,
    float* __restrict__ cs_tab, float* __restrict__ pre_out, float* __restrict__ c_soft)
{
    const int r = blockIdx.x;
    const int l = threadIdx.x;
    __shared__ float rl[REL_DIM];
    __shared__ float fA[80], fB[80];

    const float* relp = rel + (size_t)r * REL_DIM;
    for (int i = l; i < REL_DIM; i += 64) rl[i] = relp[i];
    __syncthreads();

    const float cb0 = cnn_b[0], cb1 = cnnn_b[0];
    for (int idx = l; idx < 80; idx += 64) {
        int o = 48 + idx;
        int oh = o >> 4, ow = o & 15;
        const float* base = rl + (oh * 3 - 9) * RANK + ow * 3;   // rel image rows
        float a0 = cb0, a1 = cb1;
#pragma unroll
        for (int i = 0; i < 5; ++i)
#pragma unroll
            for (int j = 0; j < 5; ++j) {
                float v = base[i * RANK + j];
                a0 = fmaf(v, cnn_w[i * 5 + j], a0);
                a1 = fmaf(v, cnnn_w[i * 5 + j], a1);
            }
        fA[idx] = a0; fB[idx] = a1;
    }
    __syncthreads();

    if (l < 18) {
        int e = (l < 9) ? l : (l - 9);
        const float* w = ((l < 9) ? (h2e_w + e * 128) : (h2en_w + e * 128)) + 48;
        const float* f = (l < 9) ? fA : fB;
        float acc = 0.f;
#pragma unroll 8
        for (int t = 0; t < 80; ++t) acc = fmaf(f[t], w[t], acc);
        pre_out[r * 18 + l] = acc;
    }
    if (l == 63) c_soft[r] = softplusf(c_param[r]);

    const float2* rd2 = (const float2*)(rel_diag + (size_t)r * DIM);
    float2* cs2 = (float2*)(cs_tab + (size_t)r * DIM);
    for (int u = l; u < 225; u += 64) {
        float2 v = rd2[u];
        float nrm = fmaxf(sqrtf(v.x * v.x + v.y * v.y), 1e-15f);
        cs2[u] = make_float2(v.x / nrm, v.y / nrm);
    }
}

// Persistent single-wave blocks: 8192 blocks x 1 wave x SPB=4 samples.
// Cross-sample software pipeline: while computing sample s, sample s+1's head
// loads (entity[q0] row, rel row, noise, pre, bh/bt/c) are in flight. The HBM
// head-miss is paid once per block (pipeline fill), not once per sample.
// No barriers anywhere: softmax/top-k scalars move via register shuffles
// (all-lane redundant top-3, wave-uniform branches, bitwise-identical chain).
__global__ __launch_bounds__(64) void k_main(
    const int* __restrict__ queries, const int* __restrict__ these_queries,
    const float* __restrict__ entity, const float* __restrict__ rel,
    const float* __restrict__ bh, const float* __restrict__ bt,
    const float* __restrict__ cnn_w, const float* __restrict__ cnn_b,
    const float* __restrict__ h2e_w, const float* __restrict__ h2e_b,
    const float* __restrict__ cnnn_w, const float* __restrict__ cnnn_b,
    const float* __restrict__ h2en_w, const float* __restrict__ h2en_b,
    const float* __restrict__ noise,
    const float* __restrict__ cs_tab, const float* __restrict__ pre_out,
    const float* __restrict__ c_soft,
    float* __restrict__ y_out, float* __restrict__ ws_rows)
{
    const int l = threadIdx.x;

    __shared__ __align__(16) float  xs[552];    // image rows 0..10: head(450) ++ rel[0:100]
    __shared__ __align__(16) float2 fs[51];     // (feat, featn) per o<48, padded 1/16
    float2* xs2 = (float2*)xs;

    const int base = blockIdx.x * SPB;

    // ---- prologue: issue sample 'base' head loads ----
    int q0 = queries[base * 3 + 0];
    int q1 = queries[base * 3 + 1];
    int t2 = these_queries[base * 3 + 2];
    float2 h2[4];
    {
        const float2* hp2 = (const float2*)(entity + (size_t)q0 * DIM);
#pragma unroll
        for (int k = 0; k < 4; ++k) { int i = l + 64 * k; if (i < 225) h2[k] = hp2[i]; }
    }
    float2 rr2 = make_float2(0.f, 0.f);
    if (l < 50) rr2 = ((const float2*)(rel + (size_t)q1 * REL_DIM))[l];
    float nz    = (l < NE) ? noise[(size_t)base * NE + l] : 0.f;
    float pre_v = (l < 18) ? pre_out[q1 * 18 + l] : 0.f;
    float bhv = bh[q0], btv = bt[t2], csv = c_soft[q1];

#pragma unroll
    for (int s = 0; s < SPB; ++s) {
        const int b = base + s;
        const int   cq1 = q1, ct2 = t2;
        const float cnz = nz, cpre = pre_v, cbh = bhv, cbt = btv, ccs = csv;

        // ---- stage current sample to LDS (waits only on current loads;
        //      for s>0 those were issued a full iteration ago) ----
#pragma unroll
        for (int k = 0; k < 4; ++k) { int i = l + 64 * k; if (i < 225) xs2[i] = h2[k]; }
        if (l < 50) xs2[225 + l] = rr2;
        LANE_FENCE();

        // ---- issue NEXT sample's head loads; they stay in flight under
        //      this sample's conv/dots/softmax (no barrier drains them) ----
        if (s + 1 < SPB) {
            const int nb = b + 1;
            q0 = queries[nb * 3 + 0];
            q1 = queries[nb * 3 + 1];
            t2 = these_queries[nb * 3 + 2];
            const float2* hp2 = (const float2*)(entity + (size_t)q0 * DIM);
#pragma unroll
            for (int k = 0; k < 4; ++k) { int i = l + 64 * k; if (i < 225) h2[k] = hp2[i]; }
            rr2 = make_float2(0.f, 0.f);
            if (l < 50) rr2 = ((const float2*)(rel + (size_t)q1 * REL_DIM))[l];
            nz    = (l < NE) ? noise[(size_t)nb * NE + l] : 0.f;
            pre_v = (l < 18) ? pre_out[q1 * 18 + l] : 0.f;
            bhv = bh[q0]; btv = bt[t2]; csv = c_soft[q1];
        }

        // ---- conv: sample-dependent outputs o < 48 (oh 0..2), both kernels ----
        if (l < 48) {
            int oh = l >> 4, ow = l & 15;
            const float* bp = xs + (oh * 3) * RANK + ow * 3;
            float a0 = cnn_b[0], a1 = cnnn_b[0];
#pragma unroll
            for (int i = 0; i < 5; ++i)
#pragma unroll
                for (int j = 0; j < 5; ++j) {
                    float v = bp[i * RANK + j];
                    a0 = fmaf(v, cnn_w[i * 5 + j], a0);
                    a1 = fmaf(v, cnnn_w[i * 5 + j], a1);
                }
            fs[l + (l >> 4)] = make_float2(a0, a1);
        }
        LANE_FENCE();

        // ---- 18 dots of length 48: 54 lanes, 16 terms each ----
        float acc = 0.f;
        if (l < 54) {
            int chunk = l / 18, j = l - chunk * 18;
            int e = (j < 9) ? j : (j - 9);
            const float* wrow = ((j < 9) ? (h2e_w + e * 128) : (h2en_w + e * 128)) + chunk * 16;
            int fbase = chunk * 17;   // padded chunk base
            if (j < 9) {
#pragma unroll
                for (int k = 0; k < 16; ++k) acc = fmaf(fs[fbase + k].x, wrow[k], acc);
            } else {
#pragma unroll
                for (int k = 0; k < 16; ++k) acc = fmaf(fs[fbase + k].y, wrow[k], acc);
            }
        }
        float pA = __shfl_down(acc, 18);
        float pB = __shfl_down(acc, 36);
        float tot = acc + pA + pB;                // valid for l < 18

        // expert e: clean on lane e, stdv on lane 9+e (identical arithmetic to LDS version)
        float myv = 0.f;
        if (l < 9)       myv = tot + cpre + h2e_b[l];
        else if (l < 18) myv = softplusf(tot + cpre + h2en_b[l - 9]) + 0.01f;
        float sd = __shfl_down(myv, 9);           // lane e<9: stdv_e
        float nv = fmaf(cnz, sd, myv);            // lane e<9: noisy_e

        // ---- top-3 of 9: every lane runs the identical serial chain over
        //      shuffled values (wave-uniform data -> uniform branches) ----
        int i0 = -1, i1 = -1;
        float v0 = -__builtin_huge_valf(), v1 = v0, v2 = v0;
#pragma unroll
        for (int e = 0; e < NE; ++e) {
            float v = __shfl(nv, e);
            if (v > v0)      { v2 = v1; v1 = v0; i1 = i0; v0 = v; i0 = e; }
            else if (v > v1) { v2 = v1; v1 = v; i1 = e; }
            else if (v > v2) { v2 = v; }
        }
        float e1 = expf(v1 - v0);
        float inv = 1.f / (1.f + e1);
        float g0 = inv, g1 = e1 * inv;
        float thr_in = v2, thr_out = v1;          // 3rd / 2nd

        // shuffles for the prob epilogue, executed by ALL lanes (no divergent shfl)
        int srcl = (l >= 9 && l < 18) ? (l - 9) : 0;
        float cl_e = __shfl(myv, srcl);           // clean_e for lane 9+e
        float nv_e = __shfl(nv, srcl);            // noisy_e for lane 9+e

        // ---- Givens + dist2 for the 2 selected experts; lanes 0-24 & 32-56 ----
        float contrib = 0.f;
        bool act = (l < 25) || (l >= 32 && l < 57);
        if (act) {
            int sel = (l >= 32) ? 1 : 0;
            int p = l - 32 * sel;
            int e = sel ? i1 : i0;
            int u = e * 25 + p;
            float2 cs = *(const float2*)(cs_tab + (size_t)cq1 * DIM + 2 * u);
            float2 rl = *(const float2*)(rel + (size_t)cq1 * REL_DIM + e * 100 + 2 * p);
            float2 rh = *(const float2*)(entity + (size_t)ct2 * DIM + 2 * u);
            float2 x  = xs2[u];
            float o0 = cs.x * x.x - cs.y * x.y + rl.x;
            float o1 = cs.y * x.x + cs.x * x.y + rl.y;
            float d0 = o0 - rh.x, d1 = o1 - rh.y;
            contrib = fmaf(d0, d0, d1 * d1);
        }

        // ---- epilogue: gates/probs (row-major ws) while Givens loads fly ----
        if (l < NE) {
            float g = (l == i0) ? g0 : ((l == i1) ? g1 : 0.f);
            ws_rows[(size_t)b * 18 + l] = g;
        } else if (l < 18) {
            float thr = (nv_e > thr_in) ? thr_in : thr_out;
            ws_rows[(size_t)b * 18 + l] = phif((cl_e - thr) / myv);
        }

        // reduce contrib within each 32-lane half (xor stays inside the half)
#pragma unroll
        for (int off = 16; off; off >>= 1) contrib += __shfl_xor(contrib, off);
        float d2b = __shfl(contrib, 32);
        if (l == 0) {
            float bsum = cbh + cbt;
            float sacc = expf(bsum - ccs * contrib) + expf(bsum - ccs * d2b);
            y_out[b] = logf((sacc == 0.f) ? EPSV : sacc);
        }
        LANE_FENCE();   // order next iteration's xs stage after this iteration's xs reads
    }
}

// 256 blocks x 64 threads; each thread accumulates 2 rows' 18 values in regs.
__global__ __launch_bounds__(64) void k_reduce(const float* __restrict__ ws_rows,
                                               float* __restrict__ partials)
{
    const int blk = blockIdx.x, t = threadIdx.x;
    float acc[18];
#pragma unroll
    for (int j = 0; j < 18; ++j) acc[j] = 0.f;
    const int r0 = blk * 128 + t * 2;
#pragma unroll
    for (int rr = 0; rr < 2; ++rr) {
        const float2* row = (const float2*)(ws_rows + (size_t)(r0 + rr) * 18);
#pragma unroll
        for (int j = 0; j < 9; ++j) {
            float2 v = row[j];
            acc[2 * j] += v.x; acc[2 * j + 1] += v.y;
        }
    }
#pragma unroll
    for (int j = 0; j < 18; ++j) {
        float v = acc[j];
        for (int off = 32; off; off >>= 1) v += __shfl_down(v, off);
        if (t == 0) partials[blk * 18 + j] = v;
    }
}

// 1 block: stage-2 reduce of 256 partials per column + cv^2 loss.
// Loads batched 16-wide (independent, latency-overlapped); add order is the
// bitwise-identical serial p=0..255 ascending order.
__global__ __launch_bounds__(64) void k_loss(const float* __restrict__ partials,
                                             float* __restrict__ out)
{
    __shared__ float sums[18];
    const int t = threadIdx.x;
    if (t < 18) {
        float s = 0.f;
        for (int p0 = 0; p0 < 256; p0 += 16) {
            float v[16];
#pragma unroll
            for (int k = 0; k < 16; ++k) v[k] = partials[(p0 + k) * 18 + t];
#pragma unroll
            for (int k = 0; k < 16; ++k) s += v[k];
        }
        sums[t] = s;
    }
    __syncthreads();
    if (t == 0) {
        float loss = 0.f;
#pragma unroll
        for (int part = 0; part < 2; ++part) {
            const float* v = sums + part * NE;
            float mean = 0.f;
            for (int i = 0; i < NE; ++i) mean += v[i];
            mean /= 9.f;
            float var = 0.f;
            for (int i = 0; i < NE; ++i) { float d = v[i] - mean; var += d * d; }
            var /= 8.f;                   // ddof=1
            loss += var / (mean * mean + 1e-10f);
        }
        out[BATCH] = 0.01f * loss;
    }
}

extern "C" void kernel_launch(void* const* d_in, const int* in_sizes, int n_in,
                              void* d_out, int out_size, void* d_ws, size_t ws_size,
                              hipStream_t stream)
{
    const int*   queries = (const int*)d_in[0];
    const int*   these   = (const int*)d_in[1];
    const float* entity  = (const float*)d_in[2];
    const float* rel     = (const float*)d_in[3];
    const float* rel_dg  = (const float*)d_in[4];
    const float* bh      = (const float*)d_in[5];
    const float* bt      = (const float*)d_in[6];
    const float* c_par   = (const float*)d_in[7];
    const float* cnn_w   = (const float*)d_in[8];
    const float* cnn_b   = (const float*)d_in[9];
    const float* h2e_w   = (const float*)d_in[10];
    const float* h2e_b   = (const float*)d_in[11];
    const float* cnnn_w  = (const float*)d_in[12];
    const float* cnnn_b  = (const float*)d_in[13];
    const float* h2en_w  = (const float*)d_in[14];
    const float* h2en_b  = (const float*)d_in[15];
    const float* noise   = (const float*)d_in[16];

    float* y  = (float*)d_out;
    float* ws = (float*)d_ws;
    float* ws_rows  = ws;                                     // BATCH*18
    float* partials = ws + (size_t)BATCH * 18;                // 256*18
    float* cs_tab   = partials + 256 * 18;                    // 22*450
    float* pre_out  = cs_tab + N_REL * DIM;                   // 22*18
    float* c_soft   = pre_out + N_REL * 18;                   // 22

    k_pre<<<N_REL, 64, 0, stream>>>(rel, rel_dg, c_par, cnn_w, cnn_b, cnnn_w, cnnn_b,
                                    h2e_w, h2en_w, cs_tab, pre_out, c_soft);
    k_main<<<BATCH / SPB, 64, 0, stream>>>(queries, these, entity, rel, bh, bt,
                                           cnn_w, cnn_b, h2e_w, h2e_b, cnnn_w, cnnn_b,
                                           h2en_w, h2en_b, noise, cs_tab, pre_out, c_soft,
                                           y, ws_rows);
    k_reduce<<<256, 64, 0, stream>>>(ws_rows, partials);
    k_loss<<<1, 64, 0, stream>>>(partials, y);
}

// Round 6
// 184.054 us; speedup vs baseline: 1.0527x; 1.0527x over previous
//
#include <hip/hip_runtime.h>
#include <math.h>

#define BATCH 32768
#define NE 9
#define RANK 50
#define DIM 450            // NE * RANK
#define REL_DIM 900        // 2 * DIM
#define N_REL 22
#define EPSV 2.2204460492503131e-16f

// Zero-instruction compiler fence at LDS write->read handoffs. Single-wave
// blocks: in-wave DS ops complete in order, so no s_barrier / waitcnt drain
// is needed (r5 validated correctness of this, absmax 0.0).
#define LANE_FENCE() asm volatile("" ::: "memory")

__device__ __forceinline__ float softplusf(float x) {
    return (x > 20.f) ? x : log1pf(expf(x));
}
__device__ __forceinline__ float phif(float z) {
    return 0.5f * (1.f + erff(z * 0.70710678118654752f));
}

// Per-relation precompute: pure-rel conv outputs' dot contributions (o in [48,128)),
// Givens cos/sin table, softplus(c). 22 blocks.
__global__ __launch_bounds__(64) void k_pre(
    const float* __restrict__ rel, const float* __restrict__ rel_diag,
    const float* __restrict__ c_param,
    const float* __restrict__ cnn_w, const float* __restrict__ cnn_b,
    const float* __restrict__ cnnn_w, const float* __restrict__ cnnn_b,
    const float* __restrict__ h2e_w, const float* __restrict__ h2en_w,
    float* __restrict__ cs_tab, float* __restrict__ pre_out, float* __restrict__ c_soft)
{
    const int r = blockIdx.x;
    const int l = threadIdx.x;
    __shared__ float rl[REL_DIM];
    __shared__ float fA[80], fB[80];

    const float* relp = rel + (size_t)r * REL_DIM;
    for (int i = l; i < REL_DIM; i += 64) rl[i] = relp[i];
    __syncthreads();

    const float cb0 = cnn_b[0], cb1 = cnnn_b[0];
    for (int idx = l; idx < 80; idx += 64) {
        int o = 48 + idx;
        int oh = o >> 4, ow = o & 15;
        const float* base = rl + (oh * 3 - 9) * RANK + ow * 3;   // rel image rows
        float a0 = cb0, a1 = cb1;
#pragma unroll
        for (int i = 0; i < 5; ++i)
#pragma unroll
            for (int j = 0; j < 5; ++j) {
                float v = base[i * RANK + j];
                a0 = fmaf(v, cnn_w[i * 5 + j], a0);
                a1 = fmaf(v, cnnn_w[i * 5 + j], a1);
            }
        fA[idx] = a0; fB[idx] = a1;
    }
    __syncthreads();

    if (l < 18) {
        int e = (l < 9) ? l : (l - 9);
        const float* w = ((l < 9) ? (h2e_w + e * 128) : (h2en_w + e * 128)) + 48;
        const float* f = (l < 9) ? fA : fB;
        float acc = 0.f;
#pragma unroll 8
        for (int t = 0; t < 80; ++t) acc = fmaf(f[t], w[t], acc);
        pre_out[r * 18 + l] = acc;
    }
    if (l == 63) c_soft[r] = softplusf(c_param[r]);

    const float2* rd2 = (const float2*)(rel_diag + (size_t)r * DIM);
    float2* cs2 = (float2*)(cs_tab + (size_t)r * DIM);
    for (int u = l; u < 225; u += 64) {
        float2 v = rd2[u];
        float nrm = fmaxf(sqrtf(v.x * v.x + v.y * v.y), 1e-15f);
        cs2[u] = make_float2(v.x / nrm, v.y / nrm);
    }
}

// One 64-lane wave per sample, 32768 blocks (max TLP — measured best grid).
// vs round-0 baseline: (1) ZERO barriers (single-wave block; in-wave DS order
// suffices; no vmcnt(0) drains, so head loads stay in flight under conv);
// (2) softmax/top-k entirely in registers via shuffles (no LDS round-trip);
// (3) wave-uniform indices forced to SGPRs (s_load scalars, saddr-form
// global loads — r2 measured −3.2 µs of VALU time from this alone).
__global__ __launch_bounds__(64) void k_main(
    const int* __restrict__ queries, const int* __restrict__ these_queries,
    const float* __restrict__ entity, const float* __restrict__ rel,
    const float* __restrict__ bh, const float* __restrict__ bt,
    const float* __restrict__ cnn_w, const float* __restrict__ cnn_b,
    const float* __restrict__ h2e_w, const float* __restrict__ h2e_b,
    const float* __restrict__ cnnn_w, const float* __restrict__ cnnn_b,
    const float* __restrict__ h2en_w, const float* __restrict__ h2en_b,
    const float* __restrict__ noise,
    const float* __restrict__ cs_tab, const float* __restrict__ pre_out,
    const float* __restrict__ c_soft,
    float* __restrict__ y_out, float* __restrict__ ws_rows)
{
    const int b = blockIdx.x;
    const int l = threadIdx.x;

    __shared__ __align__(16) float  xs[552];    // image rows 0..10: head(450) ++ rel[0:100]
    __shared__ __align__(16) float2 fs[51];     // (feat, featn) per o<48, padded 1/16
    float2* xs2 = (float2*)xs;

    const int q0 = __builtin_amdgcn_readfirstlane(queries[b * 3 + 0]);
    const int q1 = __builtin_amdgcn_readfirstlane(queries[b * 3 + 1]);
    const int t2 = __builtin_amdgcn_readfirstlane(these_queries[b * 3 + 2]);

    // ---- issue head loads (q0 row, rel row, noise, pre, scalars) ----
    float2 h2[4];
    {
        const float2* hp2 = (const float2*)(entity + (size_t)q0 * DIM);
#pragma unroll
        for (int k = 0; k < 4; ++k) { int i = l + 64 * k; if (i < 225) h2[k] = hp2[i]; }
    }
    float2 rr2 = make_float2(0.f, 0.f);
    if (l < 50) rr2 = ((const float2*)(rel + (size_t)q1 * REL_DIM))[l];
    float nz    = (l < NE) ? noise[(size_t)b * NE + l] : 0.f;
    float pre_v = (l < 18) ? pre_out[q1 * 18 + l] : 0.f;
    float bhv = bh[q0], btv = bt[t2], csv = c_soft[q1];

    // ---- stage to LDS (no barrier needed: single wave, DS in-order) ----
#pragma unroll
    for (int k = 0; k < 4; ++k) { int i = l + 64 * k; if (i < 225) xs2[i] = h2[k]; }
    if (l < 50) xs2[225 + l] = rr2;
    LANE_FENCE();

    // ---- conv: sample-dependent outputs o < 48 (oh 0..2), both kernels ----
    if (l < 48) {
        int oh = l >> 4, ow = l & 15;
        const float* bp = xs + (oh * 3) * RANK + ow * 3;
        float a0 = cnn_b[0], a1 = cnnn_b[0];
#pragma unroll
        for (int i = 0; i < 5; ++i)
#pragma unroll
            for (int j = 0; j < 5; ++j) {
                float v = bp[i * RANK + j];
                a0 = fmaf(v, cnn_w[i * 5 + j], a0);
                a1 = fmaf(v, cnnn_w[i * 5 + j], a1);
            }
        fs[l + (l >> 4)] = make_float2(a0, a1);
    }
    LANE_FENCE();

    // ---- 18 dots of length 48: 54 lanes, 16 terms each ----
    float acc = 0.f;
    if (l < 54) {
        int chunk = l / 18, j = l - chunk * 18;
        int e = (j < 9) ? j : (j - 9);
        const float* wrow = ((j < 9) ? (h2e_w + e * 128) : (h2en_w + e * 128)) + chunk * 16;
        int fbase = chunk * 17;   // padded chunk base
        if (j < 9) {
#pragma unroll
            for (int k = 0; k < 16; ++k) acc = fmaf(fs[fbase + k].x, wrow[k], acc);
        } else {
#pragma unroll
            for (int k = 0; k < 16; ++k) acc = fmaf(fs[fbase + k].y, wrow[k], acc);
        }
    }
    float pA = __shfl_down(acc, 18);
    float pB = __shfl_down(acc, 36);
    float tot = acc + pA + pB;                // valid for l < 18

    // expert e: clean on lane e, stdv on lane 9+e (identical arithmetic to r0)
    float myv = 0.f;
    if (l < 9)       myv = tot + pre_v + h2e_b[l];
    else if (l < 18) myv = softplusf(tot + pre_v + h2en_b[l - 9]) + 0.01f;
    float sd = __shfl_down(myv, 9);           // lane e<9: stdv_e
    float nv = fmaf(nz, sd, myv);             // lane e<9: noisy_e

    // ---- top-3 of 9: all lanes run the identical serial chain over
    //      shuffled values (wave-uniform -> uniform branches, no LDS) ----
    int i0 = -1, i1 = -1;
    float v0 = -__builtin_huge_valf(), v1 = v0, v2 = v0;
#pragma unroll
    for (int e = 0; e < NE; ++e) {
        float v = __shfl(nv, e);
        if (v > v0)      { v2 = v1; v1 = v0; i1 = i0; v0 = v; i0 = e; }
        else if (v > v1) { v2 = v1; v1 = v; i1 = e; }
        else if (v > v2) { v2 = v; }
    }
    float e1 = expf(v1 - v0);
    float inv = 1.f / (1.f + e1);
    float g0 = inv, g1 = e1 * inv;
    float thr_in = v2, thr_out = v1;          // 3rd / 2nd

    // shuffles for the prob epilogue, executed by ALL lanes (no divergent shfl)
    int srcl = (l >= 9 && l < 18) ? (l - 9) : 0;
    float cl_e = __shfl(myv, srcl);           // clean_e for lane 9+e
    float nv_e = __shfl(nv, srcl);            // noisy_e for lane 9+e

    // ---- Givens + dist2 for the 2 selected experts; lanes 0-24 & 32-56 ----
    float contrib = 0.f;
    bool act = (l < 25) || (l >= 32 && l < 57);
    if (act) {
        int sel = (l >= 32) ? 1 : 0;
        int p = l - 32 * sel;
        int e = sel ? i1 : i0;
        int u = e * 25 + p;
        float2 cs = *(const float2*)(cs_tab + (size_t)q1 * DIM + 2 * u);
        float2 rl = *(const float2*)(rel + (size_t)q1 * REL_DIM + e * 100 + 2 * p);
        float2 rh = *(const float2*)(entity + (size_t)t2 * DIM + 2 * u);
        float2 x  = xs2[u];
        float o0 = cs.x * x.x - cs.y * x.y + rl.x;
        float o1 = cs.y * x.x + cs.x * x.y + rl.y;
        float d0 = o0 - rh.x, d1 = o1 - rh.y;
        contrib = fmaf(d0, d0, d1 * d1);
    }

    // ---- epilogue: gates/probs (row-major ws) while Givens loads fly ----
    if (l < NE) {
        float g = (l == i0) ? g0 : ((l == i1) ? g1 : 0.f);
        ws_rows[(size_t)b * 18 + l] = g;
    } else if (l < 18) {
        float thr = (nv_e > thr_in) ? thr_in : thr_out;
        ws_rows[(size_t)b * 18 + l] = phif((cl_e - thr) / myv);
    }

    // reduce contrib within each 32-lane half (xor stays inside the half)
#pragma unroll
    for (int off = 16; off; off >>= 1) contrib += __shfl_xor(contrib, off);
    float d2b = __shfl(contrib, 32);
    if (l == 0) {
        float bsum = bhv + btv;
        float sacc = expf(bsum - csv * contrib) + expf(bsum - csv * d2b);
        y_out[b] = logf((sacc == 0.f) ? EPSV : sacc);
    }
}

// 256 blocks x 64 threads; each thread accumulates 2 rows' 18 values in regs.
__global__ __launch_bounds__(64) void k_reduce(const float* __restrict__ ws_rows,
                                               float* __restrict__ partials)
{
    const int blk = blockIdx.x, t = threadIdx.x;
    float acc[18];
#pragma unroll
    for (int j = 0; j < 18; ++j) acc[j] = 0.f;
    const int r0 = blk * 128 + t * 2;
#pragma unroll
    for (int rr = 0; rr < 2; ++rr) {
        const float2* row = (const float2*)(ws_rows + (size_t)(r0 + rr) * 18);
#pragma unroll
        for (int j = 0; j < 9; ++j) {
            float2 v = row[j];
            acc[2 * j] += v.x; acc[2 * j + 1] += v.y;
        }
    }
#pragma unroll
    for (int j = 0; j < 18; ++j) {
        float v = acc[j];
        for (int off = 32; off; off >>= 1) v += __shfl_down(v, off);
        if (t == 0) partials[blk * 18 + j] = v;
    }
}

// 1 block: stage-2 reduce of 256 partials per column + cv^2 loss.
// Loads batched 16-wide (independent, latency-overlapped); add order is the
// bitwise-identical serial p=0..255 ascending order.
__global__ __launch_bounds__(64) void k_loss(const float* __restrict__ partials,
                                             float* __restrict__ out)
{
    __shared__ float sums[18];
    const int t = threadIdx.x;
    if (t < 18) {
        float s = 0.f;
        for (int p0 = 0; p0 < 256; p0 += 16) {
            float v[16];
#pragma unroll
            for (int k = 0; k < 16; ++k) v[k] = partials[(p0 + k) * 18 + t];
#pragma unroll
            for (int k = 0; k < 16; ++k) s += v[k];
        }
        sums[t] = s;
    }
    __syncthreads();
    if (t == 0) {
        float loss = 0.f;
#pragma unroll
        for (int part = 0; part < 2; ++part) {
            const float* v = sums + part * NE;
            float mean = 0.f;
            for (int i = 0; i < NE; ++i) mean += v[i];
            mean /= 9.f;
            float var = 0.f;
            for (int i = 0; i < NE; ++i) { float d = v[i] - mean; var += d * d; }
            var /= 8.f;                   // ddof=1
            loss += var / (mean * mean + 1e-10f);
        }
        out[BATCH] = 0.01f * loss;
    }
}

extern "C" void kernel_launch(void* const* d_in, const int* in_sizes, int n_in,
                              void* d_out, int out_size, void* d_ws, size_t ws_size,
                              hipStream_t stream)
{
    const int*   queries = (const int*)d_in[0];
    const int*   these   = (const int*)d_in[1];
    const float* entity  = (const float*)d_in[2];
    const float* rel     = (const float*)d_in[3];
    const float* rel_dg  = (const float*)d_in[4];
    const float* bh      = (const float*)d_in[5];
    const float* bt      = (const float*)d_in[6];
    const float* c_par   = (const float*)d_in[7];
    const float* cnn_w   = (const float*)d_in[8];
    const float* cnn_b   = (const float*)d_in[9];
    const float* h2e_w   = (const float*)d_in[10];
    const float* h2e_b   = (const float*)d_in[11];
    const float* cnnn_w  = (const float*)d_in[12];
    const float* cnnn_b  = (const float*)d_in[13];
    const float* h2en_w  = (const float*)d_in[14];
    const float* h2en_b  = (const float*)d_in[15];
    const float* noise   = (const float*)d_in[16];

    float* y  = (float*)d_out;
    float* ws = (float*)d_ws;
    float* ws_rows  = ws;                                     // BATCH*18
    float* partials = ws + (size_t)BATCH * 18;                // 256*18
    float* cs_tab   = partials + 256 * 18;                    // 22*450
    float* pre_out  = cs_tab + N_REL * DIM;                   // 22*18
    float* c_soft   = pre_out + N_REL * 18;                   // 22

    k_pre<<<N_REL, 64, 0, stream>>>(rel, rel_dg, c_par, cnn_w, cnn_b, cnnn_w, cnnn_b,
                                    h2e_w, h2en_w, cs_tab, pre_out, c_soft);
    k_main<<<BATCH, 64, 0, stream>>>(queries, these, entity, rel, bh, bt,
                                     cnn_w, cnn_b, h2e_w, h2e_b, cnnn_w, cnnn_b,
                                     h2en_w, h2en_b, noise, cs_tab, pre_out, c_soft,
                                     y, ws_rows);
    k_reduce<<<256, 64, 0, stream>>>(ws_rows, partials);
    k_loss<<<1, 64, 0, stream>>>(partials, y);
}

// Round 7
// 181.917 us; speedup vs baseline: 1.0650x; 1.0118x over previous
//
#include <hip/hip_runtime.h>
#include <math.h>

#define BATCH 32768
#define NE 9
#define RANK 50
#define DIM 450            // NE * RANK
#define REL_DIM 900        // 2 * DIM
#define N_REL 22
#define EPSV 2.2204460492503131e-16f
#define WPB 4              // independent waves (samples) per block — no cross-wave sync

// Zero-instruction compiler fence at LDS write->read handoffs. Each wave uses
// a PRIVATE LDS slot: in-wave DS ops complete in order, so no s_barrier and no
// waitcnt drain is needed (r5/r6 validated correctness, absmax 0.0).
#define LANE_FENCE() asm volatile("" ::: "memory")

__device__ __forceinline__ float softplusf(float x) {
    return (x > 20.f) ? x : log1pf(expf(x));
}
__device__ __forceinline__ float phif(float z) {
    return 0.5f * (1.f + erff(z * 0.70710678118654752f));
}

// Per-relation precompute: pure-rel conv outputs' dot contributions (o in [48,128)),
// Givens cos/sin table, softplus(c). 22 blocks.
__global__ __launch_bounds__(64) void k_pre(
    const float* __restrict__ rel, const float* __restrict__ rel_diag,
    const float* __restrict__ c_param,
    const float* __restrict__ cnn_w, const float* __restrict__ cnn_b,
    const float* __restrict__ cnnn_w, const float* __restrict__ cnnn_b,
    const float* __restrict__ h2e_w, const float* __restrict__ h2en_w,
    float* __restrict__ cs_tab, float* __restrict__ pre_out, float* __restrict__ c_soft)
{
    const int r = blockIdx.x;
    const int l = threadIdx.x;
    __shared__ float rl[REL_DIM];
    __shared__ float fA[80], fB[80];

    const float* relp = rel + (size_t)r * REL_DIM;
    for (int i = l; i < REL_DIM; i += 64) rl[i] = relp[i];
    __syncthreads();

    const float cb0 = cnn_b[0], cb1 = cnnn_b[0];
    for (int idx = l; idx < 80; idx += 64) {
        int o = 48 + idx;
        int oh = o >> 4, ow = o & 15;
        const float* base = rl + (oh * 3 - 9) * RANK + ow * 3;   // rel image rows
        float a0 = cb0, a1 = cb1;
#pragma unroll
        for (int i = 0; i < 5; ++i)
#pragma unroll
            for (int j = 0; j < 5; ++j) {
                float v = base[i * RANK + j];
                a0 = fmaf(v, cnn_w[i * 5 + j], a0);
                a1 = fmaf(v, cnnn_w[i * 5 + j], a1);
            }
        fA[idx] = a0; fB[idx] = a1;
    }
    __syncthreads();

    if (l < 18) {
        int e = (l < 9) ? l : (l - 9);
        const float* w = ((l < 9) ? (h2e_w + e * 128) : (h2en_w + e * 128)) + 48;
        const float* f = (l < 9) ? fA : fB;
        float acc = 0.f;
#pragma unroll 8
        for (int t = 0; t < 80; ++t) acc = fmaf(f[t], w[t], acc);
        pre_out[r * 18 + l] = acc;
    }
    if (l == 63) c_soft[r] = softplusf(c_param[r]);

    const float2* rd2 = (const float2*)(rel_diag + (size_t)r * DIM);
    float2* cs2 = (float2*)(cs_tab + (size_t)r * DIM);
    for (int u = l; u < 225; u += 64) {
        float2 v = rd2[u];
        float nrm = fmaxf(sqrtf(v.x * v.x + v.y * v.y), 1e-15f);
        cs2[u] = make_float2(v.x / nrm, v.y / nrm);
    }
}

// 4 fully-independent waves per block (one sample each, private LDS slots,
// ZERO cross-wave synchronization — no barriers, no waitcnt fences).
// Pure occupancy experiment vs the 1-wave-per-block variant: same wave body.
__global__ __launch_bounds__(256) void k_main(
    const int* __restrict__ queries, const int* __restrict__ these_queries,
    const float* __restrict__ entity, const float* __restrict__ rel,
    const float* __restrict__ bh, const float* __restrict__ bt,
    const float* __restrict__ cnn_w, const float* __restrict__ cnn_b,
    const float* __restrict__ h2e_w, const float* __restrict__ h2e_b,
    const float* __restrict__ cnnn_w, const float* __restrict__ cnnn_b,
    const float* __restrict__ h2en_w, const float* __restrict__ h2en_b,
    const float* __restrict__ noise,
    const float* __restrict__ cs_tab, const float* __restrict__ pre_out,
    const float* __restrict__ c_soft,
    float* __restrict__ y_out, float* __restrict__ ws_rows)
{
    const int w = __builtin_amdgcn_readfirstlane(threadIdx.x >> 6);
    const int l = threadIdx.x & 63;
    const int b = blockIdx.x * WPB + w;

    __shared__ __align__(16) float  xs_all[WPB][552];  // head(450) ++ rel[0:100], rows 0..10
    __shared__ __align__(16) float2 fs_all[WPB][51];   // (feat, featn) per o<48, padded 1/16
    float*  xs  = xs_all[w];
    float2* fs  = fs_all[w];
    float2* xs2 = (float2*)xs;

    const int q0 = __builtin_amdgcn_readfirstlane(queries[b * 3 + 0]);
    const int q1 = __builtin_amdgcn_readfirstlane(queries[b * 3 + 1]);
    const int t2 = __builtin_amdgcn_readfirstlane(these_queries[b * 3 + 2]);

    // ---- issue head loads (q0 row, rel row, noise, pre, scalars) ----
    float2 h2[4];
    {
        const float2* hp2 = (const float2*)(entity + (size_t)q0 * DIM);
#pragma unroll
        for (int k = 0; k < 4; ++k) { int i = l + 64 * k; if (i < 225) h2[k] = hp2[i]; }
    }
    float2 rr2 = make_float2(0.f, 0.f);
    if (l < 50) rr2 = ((const float2*)(rel + (size_t)q1 * REL_DIM))[l];
    float nz    = (l < NE) ? noise[(size_t)b * NE + l] : 0.f;
    float pre_v = (l < 18) ? pre_out[q1 * 18 + l] : 0.f;
    float bhv = bh[q0], btv = bt[t2], csv = c_soft[q1];

    // ---- stage to LDS (private slot; in-wave DS order, no barrier) ----
#pragma unroll
    for (int k = 0; k < 4; ++k) { int i = l + 64 * k; if (i < 225) xs2[i] = h2[k]; }
    if (l < 50) xs2[225 + l] = rr2;
    LANE_FENCE();

    // ---- conv: sample-dependent outputs o < 48 (oh 0..2), both kernels ----
    if (l < 48) {
        int oh = l >> 4, ow = l & 15;
        const float* bp = xs + (oh * 3) * RANK + ow * 3;
        float a0 = cnn_b[0], a1 = cnnn_b[0];
#pragma unroll
        for (int i = 0; i < 5; ++i)
#pragma unroll
            for (int j = 0; j < 5; ++j) {
                float v = bp[i * RANK + j];
                a0 = fmaf(v, cnn_w[i * 5 + j], a0);
                a1 = fmaf(v, cnnn_w[i * 5 + j], a1);
            }
        fs[l + (l >> 4)] = make_float2(a0, a1);
    }
    LANE_FENCE();

    // ---- 18 dots of length 48: 54 lanes, 16 terms each ----
    float acc = 0.f;
    if (l < 54) {
        int chunk = l / 18, j = l - chunk * 18;
        int e = (j < 9) ? j : (j - 9);
        const float* wrow = ((j < 9) ? (h2e_w + e * 128) : (h2en_w + e * 128)) + chunk * 16;
        int fbase = chunk * 17;   // padded chunk base
        if (j < 9) {
#pragma unroll
            for (int k = 0; k < 16; ++k) acc = fmaf(fs[fbase + k].x, wrow[k], acc);
        } else {
#pragma unroll
            for (int k = 0; k < 16; ++k) acc = fmaf(fs[fbase + k].y, wrow[k], acc);
        }
    }
    float pA = __shfl_down(acc, 18);
    float pB = __shfl_down(acc, 36);
    float tot = acc + pA + pB;                // valid for l < 18

    // expert e: clean on lane e, stdv on lane 9+e (identical arithmetic to r0)
    float myv = 0.f;
    if (l < 9)       myv = tot + pre_v + h2e_b[l];
    else if (l < 18) myv = softplusf(tot + pre_v + h2en_b[l - 9]) + 0.01f;
    float sd = __shfl_down(myv, 9);           // lane e<9: stdv_e
    float nv = fmaf(nz, sd, myv);             // lane e<9: noisy_e

    // ---- top-3 of 9: all lanes run the identical serial chain over
    //      shuffled values (wave-uniform -> uniform branches, no LDS) ----
    int i0 = -1, i1 = -1;
    float v0 = -__builtin_huge_valf(), v1 = v0, v2 = v0;
#pragma unroll
    for (int e = 0; e < NE; ++e) {
        float v = __shfl(nv, e);
        if (v > v0)      { v2 = v1; v1 = v0; i1 = i0; v0 = v; i0 = e; }
        else if (v > v1) { v2 = v1; v1 = v; i1 = e; }
        else if (v > v2) { v2 = v; }
    }
    float e1 = expf(v1 - v0);
    float inv = 1.f / (1.f + e1);
    float g0 = inv, g1 = e1 * inv;
    float thr_in = v2, thr_out = v1;          // 3rd / 2nd

    // shuffles for the prob epilogue, executed by ALL lanes (no divergent shfl)
    int srcl = (l >= 9 && l < 18) ? (l - 9) : 0;
    float cl_e = __shfl(myv, srcl);           // clean_e for lane 9+e
    float nv_e = __shfl(nv, srcl);            // noisy_e for lane 9+e

    // ---- Givens + dist2 for the 2 selected experts; lanes 0-24 & 32-56 ----
    float contrib = 0.f;
    bool act = (l < 25) || (l >= 32 && l < 57);
    if (act) {
        int sel = (l >= 32) ? 1 : 0;
        int p = l - 32 * sel;
        int e = sel ? i1 : i0;
        int u = e * 25 + p;
        float2 cs = *(const float2*)(cs_tab + (size_t)q1 * DIM + 2 * u);
        float2 rl = *(const float2*)(rel + (size_t)q1 * REL_DIM + e * 100 + 2 * p);
        float2 rh = *(const float2*)(entity + (size_t)t2 * DIM + 2 * u);
        float2 x  = xs2[u];
        float o0 = cs.x * x.x - cs.y * x.y + rl.x;
        float o1 = cs.y * x.x + cs.x * x.y + rl.y;
        float d0 = o0 - rh.x, d1 = o1 - rh.y;
        contrib = fmaf(d0, d0, d1 * d1);
    }

    // ---- epilogue: gates/probs (row-major ws) while Givens loads fly ----
    if (l < NE) {
        float g = (l == i0) ? g0 : ((l == i1) ? g1 : 0.f);
        ws_rows[(size_t)b * 18 + l] = g;
    } else if (l < 18) {
        float thr = (nv_e > thr_in) ? thr_in : thr_out;
        ws_rows[(size_t)b * 18 + l] = phif((cl_e - thr) / myv);
    }

    // reduce contrib within each 32-lane half (xor stays inside the half)
#pragma unroll
    for (int off = 16; off; off >>= 1) contrib += __shfl_xor(contrib, off);
    float d2b = __shfl(contrib, 32);
    if (l == 0) {
        float bsum = bhv + btv;
        float sacc = expf(bsum - csv * contrib) + expf(bsum - csv * d2b);
        y_out[b] = logf((sacc == 0.f) ? EPSV : sacc);
    }
}

// 256 blocks x 64 threads; each thread accumulates 2 rows' 18 values in regs.
__global__ __launch_bounds__(64) void k_reduce(const float* __restrict__ ws_rows,
                                               float* __restrict__ partials)
{
    const int blk = blockIdx.x, t = threadIdx.x;
    float acc[18];
#pragma unroll
    for (int j = 0; j < 18; ++j) acc[j] = 0.f;
    const int r0 = blk * 128 + t * 2;
#pragma unroll
    for (int rr = 0; rr < 2; ++rr) {
        const float2* row = (const float2*)(ws_rows + (size_t)(r0 + rr) * 18);
#pragma unroll
        for (int j = 0; j < 9; ++j) {
            float2 v = row[j];
            acc[2 * j] += v.x; acc[2 * j + 1] += v.y;
        }
    }
#pragma unroll
    for (int j = 0; j < 18; ++j) {
        float v = acc[j];
        for (int off = 32; off; off >>= 1) v += __shfl_down(v, off);
        if (t == 0) partials[blk * 18 + j] = v;
    }
}

// 1 block: stage-2 reduce of 256 partials per column + cv^2 loss.
// Loads batched 16-wide (independent, latency-overlapped); add order is the
// bitwise-identical serial p=0..255 ascending order.
__global__ __launch_bounds__(64) void k_loss(const float* __restrict__ partials,
                                             float* __restrict__ out)
{
    __shared__ float sums[18];
    const int t = threadIdx.x;
    if (t < 18) {
        float s = 0.f;
        for (int p0 = 0; p0 < 256; p0 += 16) {
            float v[16];
#pragma unroll
            for (int k = 0; k < 16; ++k) v[k] = partials[(p0 + k) * 18 + t];
#pragma unroll
            for (int k = 0; k < 16; ++k) s += v[k];
        }
        sums[t] = s;
    }
    __syncthreads();
    if (t == 0) {
        float loss = 0.f;
#pragma unroll
        for (int part = 0; part < 2; ++part) {
            const float* v = sums + part * NE;
            float mean = 0.f;
            for (int i = 0; i < NE; ++i) mean += v[i];
            mean /= 9.f;
            float var = 0.f;
            for (int i = 0; i < NE; ++i) { float d = v[i] - mean; var += d * d; }
            var /= 8.f;                   // ddof=1
            loss += var / (mean * mean + 1e-10f);
        }
        out[BATCH] = 0.01f * loss;
    }
}

extern "C" void kernel_launch(void* const* d_in, const int* in_sizes, int n_in,
                              void* d_out, int out_size, void* d_ws, size_t ws_size,
                              hipStream_t stream)
{
    const int*   queries = (const int*)d_in[0];
    const int*   these   = (const int*)d_in[1];
    const float* entity  = (const float*)d_in[2];
    const float* rel     = (const float*)d_in[3];
    const float* rel_dg  = (const float*)d_in[4];
    const float* bh      = (const float*)d_in[5];
    const float* bt      = (const float*)d_in[6];
    const float* c_par   = (const float*)d_in[7];
    const float* cnn_w   = (const float*)d_in[8];
    const float* cnn_b   = (const float*)d_in[9];
    const float* h2e_w   = (const float*)d_in[10];
    const float* h2e_b   = (const float*)d_in[11];
    const float* cnnn_w  = (const float*)d_in[12];
    const float* cnnn_b  = (const float*)d_in[13];
    const float* h2en_w  = (const float*)d_in[14];
    const float* h2en_b  = (const float*)d_in[15];
    const float* noise   = (const float*)d_in[16];

    float* y  = (float*)d_out;
    float* ws = (float*)d_ws;
    float* ws_rows  = ws;                                     // BATCH*18
    float* partials = ws + (size_t)BATCH * 18;                // 256*18
    float* cs_tab   = partials + 256 * 18;                    // 22*450
    float* pre_out  = cs_tab + N_REL * DIM;                   // 22*18
    float* c_soft   = pre_out + N_REL * 18;                   // 22

    k_pre<<<N_REL, 64, 0, stream>>>(rel, rel_dg, c_par, cnn_w, cnn_b, cnnn_w, cnnn_b,
                                    h2e_w, h2en_w, cs_tab, pre_out, c_soft);
    k_main<<<BATCH / WPB, 256, 0, stream>>>(queries, these, entity, rel, bh, bt,
                                            cnn_w, cnn_b, h2e_w, h2e_b, cnnn_w, cnnn_b,
                                            h2en_w, h2en_b, noise, cs_tab, pre_out, c_soft,
                                            y, ws_rows);
    k_reduce<<<256, 64, 0, stream>>>(ws_rows, partials);
    k_loss<<<1, 64, 0, stream>>>(partials, y);
}